// Round 2
// baseline (387.922 us; speedup 1.0000x reference)
//
#include <hip/hip_runtime.h>

#define NPTS 2048
#define LVLS 16
#define TS   524288        // 2^19 hash entries per level -> mask TS-1
#define FEAT 8
#define ROWS_PER_BLK 64
#define COLS_PER_THR 4
#define BLK 256
#define OUT_W (LVLS * NPTS)   // 32768

typedef float vfloat4 __attribute__((ext_vector_type(4)));

// out[i, l*N + j] = base_j + fx_i*dx_j + fy_i*dy_j + fz_i*dz_j   (1/3 folded in)
// base = (f0+f2+f4)/3, dx=(f1-f0)/3, dy=(f3-f2)/3, dz=(f5-f4)/3
__global__ __launch_bounds__(BLK) void mrhe_kernel(const float* __restrict__ x,
                                                   const float* __restrict__ tables,
                                                   float* __restrict__ out) {
    // blockIdx.x in [0,32): 2 column-chunks of 1024 per level, 16 levels
    const int chunk = blockIdx.x;
    const int level = chunk >> 1;
    const int col0  = (chunk & 1) * (BLK * COLS_PER_THR) + threadIdx.x * COLS_PER_THR; // col within level
    const int row0  = blockIdx.y * ROWS_PER_BLK;

    const float gridres = (float)(1 << (level + 1));

    __shared__ float fr[ROWS_PER_BLK][4];
    if (threadIdx.x < ROWS_PER_BLK) {
        const int i = row0 + threadIdx.x;
        const float sx = x[i * 3 + 0] * gridres;
        const float sy = x[i * 3 + 1] * gridres;
        const float sz = x[i * 3 + 2] * gridres;
        fr[threadIdx.x][0] = sx - floorf(sx);
        fr[threadIdx.x][1] = sy - floorf(sy);
        fr[threadIdx.x][2] = sz - floorf(sz);
        fr[threadIdx.x][3] = 0.0f;
    }

    // per-thread column data (4 columns)
    vfloat4 base, dx, dy, dz;
    const float* tl = tables + (size_t)level * TS * FEAT;
    const float third = 1.0f / 3.0f;
#pragma unroll
    for (int c = 0; c < COLS_PER_THR; ++c) {
        const int j = col0 + c;
        const float sx = x[j * 3 + 0] * gridres;
        const float sy = x[j * 3 + 1] * gridres;
        const float sz = x[j * 3 + 2] * gridres;
        // coords are in [0,1) so floor values are non-negative; sum < 3*2^16 < 2^19
        const int h = ((int)floorf(sx) + (int)floorf(sy) + (int)floorf(sz)) & (TS - 1);
        const vfloat4* fp = (const vfloat4*)(tl + (size_t)h * FEAT);
        const vfloat4 f03 = fp[0];   // f0 f1 f2 f3
        const vfloat4 f47 = fp[1];   // f4 f5 f6 f7
        base[c] = (f03.x + f03.z + f47.x) * third;
        dx[c]   = (f03.y - f03.x) * third;
        dy[c]   = (f03.w - f03.z) * third;
        dz[c]   = (f47.y - f47.x) * third;
    }
    __syncthreads();

    float* orow = out + (size_t)row0 * OUT_W + (size_t)level * NPTS + col0;
#pragma unroll 4
    for (int i = 0; i < ROWS_PER_BLK; ++i) {
        const float fx = fr[i][0];
        const float fy = fr[i][1];
        const float fz = fr[i][2];
        vfloat4 o = base + fx * dx + fy * dy + fz * dz;
        __builtin_nontemporal_store(o, (vfloat4*)orow);  // write-only stream
        orow += OUT_W;
    }
}

extern "C" void kernel_launch(void* const* d_in, const int* in_sizes, int n_in,
                              void* d_out, int out_size, void* d_ws, size_t ws_size,
                              hipStream_t stream) {
    const float* x      = (const float*)d_in[0];   // [2048, 3]
    const float* tables = (const float*)d_in[1];   // [16, 524288, 8]
    float* out = (float*)d_out;                    // [2048, 16*2048]

    dim3 grid(LVLS * 2, NPTS / ROWS_PER_BLK);      // 32 x 32 = 1024 blocks
    dim3 block(BLK);
    mrhe_kernel<<<grid, block, 0, stream>>>(x, tables, out);
}

// Round 3
// 384.480 us; speedup vs baseline: 1.0090x; 1.0090x over previous
//
#include <hip/hip_runtime.h>

#define NPTS 2048
#define LVLS 16
#define TS   524288        // 2^19 hash entries per level -> mask TS-1
#define FEAT 8
#define ROWS_PER_BLK 64
#define COLS_PER_THR 4
#define BLK 256
#define OUT_W (LVLS * NPTS)   // 32768

typedef float vfloat4 __attribute__((ext_vector_type(4)));

// out[i, l*N + j] = base_j + fx_i*dx_j + fy_i*dy_j + fz_i*dz_j   (1/3 folded in)
// base = (f0+f2+f4)/3, dx=(f1-f0)/3, dy=(f3-f2)/3, dz=(f5-f4)/3
__global__ __launch_bounds__(BLK) void mrhe_kernel(const float* __restrict__ x,
                                                   const float* __restrict__ tables,
                                                   float* __restrict__ out) {
    // blockIdx.x in [0,32): 2 column-chunks of 1024 per level, 16 levels
    const int chunk = blockIdx.x;
    const int level = chunk >> 1;
    const int col0  = (chunk & 1) * (BLK * COLS_PER_THR) + threadIdx.x * COLS_PER_THR; // col within level
    const int row0  = blockIdx.y * ROWS_PER_BLK;

    const float gridres = (float)(1 << (level + 1));

    __shared__ vfloat4 fr[ROWS_PER_BLK];
    if (threadIdx.x < ROWS_PER_BLK) {
        const int i = row0 + threadIdx.x;
        const float sx = x[i * 3 + 0] * gridres;
        const float sy = x[i * 3 + 1] * gridres;
        const float sz = x[i * 3 + 2] * gridres;
        vfloat4 f;
        f.x = sx - floorf(sx);
        f.y = sy - floorf(sy);
        f.z = sz - floorf(sz);
        f.w = 0.0f;
        fr[threadIdx.x] = f;
    }

    // per-thread column data (4 columns)
    vfloat4 base, dx, dy, dz;
    const float* tl = tables + (size_t)level * TS * FEAT;
    const float third = 1.0f / 3.0f;
#pragma unroll
    for (int c = 0; c < COLS_PER_THR; ++c) {
        const int j = col0 + c;
        const float sx = x[j * 3 + 0] * gridres;
        const float sy = x[j * 3 + 1] * gridres;
        const float sz = x[j * 3 + 2] * gridres;
        // coords are in [0,1) so floor values are non-negative; sum < 3*2^16 < 2^19
        const int h = ((int)floorf(sx) + (int)floorf(sy) + (int)floorf(sz)) & (TS - 1);
        const vfloat4* fp = (const vfloat4*)(tl + (size_t)h * FEAT);
        const vfloat4 f03 = fp[0];   // f0 f1 f2 f3
        const vfloat4 f47 = fp[1];   // f4 f5 f6 f7
        base[c] = (f03.x + f03.z + f47.x) * third;
        dx[c]   = (f03.y - f03.x) * third;
        dy[c]   = (f03.w - f03.z) * third;
        dz[c]   = (f47.y - f47.x) * third;
    }
    __syncthreads();

    float* orow = out + (size_t)row0 * OUT_W + (size_t)level * NPTS + col0;
#pragma unroll 4
    for (int i = 0; i < ROWS_PER_BLK; ++i) {
        const vfloat4 f = fr[i];          // one ds_read_b128, broadcast (no conflict)
        vfloat4 o = base + f.x * dx + f.y * dy + f.z * dz;
        *(vfloat4*)orow = o;              // plain coalesced store, streams via L2
        orow += OUT_W;
    }
}

extern "C" void kernel_launch(void* const* d_in, const int* in_sizes, int n_in,
                              void* d_out, int out_size, void* d_ws, size_t ws_size,
                              hipStream_t stream) {
    const float* x      = (const float*)d_in[0];   // [2048, 3]
    const float* tables = (const float*)d_in[1];   // [16, 524288, 8]
    float* out = (float*)d_out;                    // [2048, 16*2048]

    dim3 grid(LVLS * 2, NPTS / ROWS_PER_BLK);      // 32 x 32 = 1024 blocks
    dim3 block(BLK);
    mrhe_kernel<<<grid, block, 0, stream>>>(x, tables, out);
}